// Round 1
// baseline (139.402 us; speedup 1.0000x reference)
//
#include <hip/hip_runtime.h>

#define NN 100
#define CC 32
#define HEE 32
#define FF 64
#define TILE 10

// K1: hi = x@ew1[:C] + eb1, hj = x@ew1[C:], plus d0 = (rowsum(A)+1+1e-5)^-0.5
// grid B*N blocks of 64 (one wave)
__global__ __launch_bounds__(64) void k_hidden(
    const float* __restrict__ x, const float* __restrict__ A,
    const float* __restrict__ ew1, const float* __restrict__ eb1,
    float* __restrict__ hi, float* __restrict__ hj, float* __restrict__ d0) {
  int bn = blockIdx.x;
  int t = threadIdx.x;
  int i = bn % NN;
  __shared__ float xr[CC];
  if (t < CC) xr[t] = x[bn * CC + t];

  // A row sum (A_hat = A + I -> +1.0)
  const float* arow = A + (size_t)bn * NN;
  float s = 0.f;
  for (int j = t; j < NN; j += 64) s += arow[j];
#pragma unroll
  for (int off = 32; off > 0; off >>= 1) s += __shfl_down(s, off);
  if (t == 0) d0[bn] = 1.0f / sqrtf(s + 1.0f + 1e-5f);

  __syncthreads();
  int k = t & 31;
  const float* w = ew1 + (t < 32 ? 0 : CC * HEE) + k;
  float acc = (t < 32) ? eb1[k] : 0.f;
#pragma unroll
  for (int c = 0; c < CC; ++c) acc += xr[c] * w[c * HEE];
  if (t < 32) hi[bn * HEE + k] = acc;
  else        hj[bn * HEE + k] = acc;
}

// K2: Ahat1 = A_pred + I, d1 = (rowsum+1e-5)^-0.5
// grid B*10 blocks of 256; block owns rows i0..i0+9 of batch b
__global__ __launch_bounds__(256) void k_edge(
    const float* __restrict__ hi, const float* __restrict__ hj,
    const float* __restrict__ ew2, const float* __restrict__ eb2,
    const float* __restrict__ mask,
    float* __restrict__ Ahat1, float* __restrict__ d1) {
  __shared__ float shi[NN * HEE];   // swizzled float4 layout
  __shared__ float shj[NN * HEE];
  __shared__ float sw2[HEE];
  __shared__ float sm[NN];
  __shared__ float sA[TILE][NN];
  int t = threadIdx.x;
  int b = blockIdx.x / 10;
  int i0 = (blockIdx.x % 10) * TILE;

  const float4* hi4 = (const float4*)(hi + (size_t)b * NN * HEE);
  const float4* hj4 = (const float4*)(hj + (size_t)b * NN * HEE);
  float4* shi4 = (float4*)shi;
  float4* shj4 = (float4*)shj;
  // stage with XOR swizzle: slot = (j<<3) | (k4 ^ (j&7))  (row stride 128B -> spread banks)
  for (int v = t; v < NN * 8; v += 256) {
    int j = v >> 3, k4 = v & 7;
    int sw = (j << 3) | (k4 ^ (j & 7));
    shi4[sw] = hi4[v];
    shj4[sw] = hj4[v];
  }
  if (t < HEE) sw2[t] = ew2[t];
  if (t < NN) sm[t] = mask[b * NN + t];
  __syncthreads();

  float e2 = eb2[0];
  float4* sw24 = (float4*)sw2;
  for (int p = t; p < TILE * NN; p += 256) {
    int r = p / NN, j = p % NN, i = i0 + r;
    float val;
    if (j == i) {
      val = 1.0f;  // A_pred diag 0, +I
    } else {
      float a1 = 0.f, a2 = 0.f;
#pragma unroll
      for (int k4 = 0; k4 < 8; ++k4) {
        float4 hii = shi4[(i << 3) | (k4 ^ (i & 7))];
        float4 hji = shj4[(i << 3) | (k4 ^ (i & 7))];
        float4 hij = shi4[(j << 3) | (k4 ^ (j & 7))];
        float4 hjj = shj4[(j << 3) | (k4 ^ (j & 7))];
        float4 w4 = sw24[k4];
        a1 += fmaxf(hii.x + hjj.x, 0.f) * w4.x;
        a2 += fmaxf(hij.x + hji.x, 0.f) * w4.x;
        a1 += fmaxf(hii.y + hjj.y, 0.f) * w4.y;
        a2 += fmaxf(hij.y + hji.y, 0.f) * w4.y;
        a1 += fmaxf(hii.z + hjj.z, 0.f) * w4.z;
        a2 += fmaxf(hij.z + hji.z, 0.f) * w4.z;
        a1 += fmaxf(hii.w + hjj.w, 0.f) * w4.w;
        a2 += fmaxf(hij.w + hji.w, 0.f) * w4.w;
      }
      val = expf(0.5f * (a1 + a2) + e2) * sm[i] * sm[j];
    }
    sA[r][j] = val;
    Ahat1[((size_t)b * NN + i) * NN + j] = val;
  }
  __syncthreads();
  if (t < TILE) {
    float s = 0.f;
    for (int j = 0; j < NN; ++j) s += sA[t][j];
    d1[b * NN + i0 + t] = 1.0f / sqrtf(s + 1e-5f);
  }
}

// K3: one gconv layer. grid B*10 blocks of 256.
// LH = [L0@h, L1@h]; out = relu((LH@W + b) * mask)
template <int FIN>
__global__ __launch_bounds__(256) void k_gconv(
    const float* __restrict__ hin, const float* __restrict__ A,
    const float* __restrict__ Ahat1,
    const float* __restrict__ d0, const float* __restrict__ d1,
    const float* __restrict__ mask,
    const float* __restrict__ W, const float* __restrict__ bias,
    float* __restrict__ hout) {
  constexpr int K2 = 2 * FIN;
  __shared__ float sH[NN * FIN];
  __shared__ float sL[2][TILE][NN];
  __shared__ float sLH[TILE][K2];
  int t = threadIdx.x;
  int b = blockIdx.x / 10;
  int i0 = (blockIdx.x % 10) * TILE;

  const float4* h4 = (const float4*)(hin + (size_t)b * NN * FIN);
  float4* sH4 = (float4*)sH;
  for (int v = t; v < NN * FIN / 4; v += 256) sH4[v] = h4[v];

  const float* d0b = d0 + b * NN;
  const float* d1b = d1 + b * NN;
  for (int p = t; p < TILE * NN; p += 256) {
    int r = p / NN, j = p % NN, i = i0 + r;
    size_t idx = ((size_t)b * NN + i) * NN + j;
    float a0 = A[idx] + (i == j ? 1.f : 0.f);
    sL[0][r][j] = a0 * d0b[i] * d0b[j];
    sL[1][r][j] = Ahat1[idx] * d1b[i] * d1b[j];
  }
  __syncthreads();

  // phase 1: LH[r][tp] = sum_j L[rel][r][j] * h[j][k]
  for (int w = t; w < TILE * K2; w += 256) {
    int r = w / K2;
    int tp = w % K2;
    int rel = tp / FIN;
    int k = tp % FIN;
    const float4* Lr = (const float4*)&sL[rel][r][0];
    float acc = 0.f;
#pragma unroll
    for (int j4 = 0; j4 < NN / 4; ++j4) {
      float4 lv = Lr[j4];
      int j = j4 * 4;
      acc += lv.x * sH[j * FIN + k];
      acc += lv.y * sH[(j + 1) * FIN + k];
      acc += lv.z * sH[(j + 2) * FIN + k];
      acc += lv.w * sH[(j + 3) * FIN + k];
    }
    sLH[r][tp] = acc;
  }
  __syncthreads();

  // phase 2: out[r][f] = relu((sum_k LH[r][k]*W[k][f] + b[f]) * mask)
  for (int w = t; w < TILE * FF; w += 256) {
    int r = w / FF, f = w % FF;
    int i = i0 + r;
    float acc = bias[f];
    const float* lh = &sLH[r][0];
#pragma unroll 8
    for (int k = 0; k < K2; ++k) acc += lh[k] * W[k * FF + f];
    float z = acc * mask[b * NN + i];
    hout[((size_t)b * NN + i) * FF + f] = fmaxf(z, 0.f);
  }
}

// K4: max-pool over N + classifier. grid B blocks of 64.
__global__ __launch_bounds__(64) void k_final(
    const float* __restrict__ h, const float* __restrict__ fw,
    const float* __restrict__ fb, float* __restrict__ out) {
  int b = blockIdx.x;
  int t = threadIdx.x;
  __shared__ float sp[FF];
  float m = -3.402823466e38f;
  const float* hb = h + (size_t)b * NN * FF;
  for (int i = 0; i < NN; ++i) m = fmaxf(m, hb[i * FF + t]);
  sp[t] = m;
  __syncthreads();
  if (t < 16) {
    float acc = fb[t];
#pragma unroll
    for (int f = 0; f < FF; ++f) acc += sp[f] * fw[f * 16 + t];
    out[b * 16 + t] = acc;
  }
}

extern "C" void kernel_launch(void* const* d_in, const int* in_sizes, int n_in,
                              void* d_out, int out_size, void* d_ws, size_t ws_size,
                              hipStream_t stream) {
  const float* x    = (const float*)d_in[0];
  const float* A    = (const float*)d_in[1];
  const float* mask = (const float*)d_in[2];
  const float* ew1  = (const float*)d_in[3];
  const float* eb1  = (const float*)d_in[4];
  const float* ew2  = (const float*)d_in[5];
  const float* eb2  = (const float*)d_in[6];
  const float* gw0  = (const float*)d_in[7];
  const float* gb0  = (const float*)d_in[8];
  const float* gw1  = (const float*)d_in[9];
  const float* gb1  = (const float*)d_in[10];
  const float* gw2  = (const float*)d_in[11];
  const float* gb2  = (const float*)d_in[12];
  const float* fw   = (const float*)d_in[13];
  const float* fb   = (const float*)d_in[14];
  float* out = (float*)d_out;
  float* ws = (float*)d_ws;

  const int B = 128;
  float* hi  = ws;                  // 128*100*32 = 409600
  float* hj  = hi + 409600;         // 409600
  float* Ah1 = hj + 409600;         // 128*100*100 = 1280000
  float* d0  = Ah1 + 1280000;       // 12800
  float* d1  = d0 + 12800;          // 12800
  float* h0  = d1 + 12800;          // 128*100*64 = 819200
  float* h1  = h0 + 819200;         // 819200

  k_hidden<<<B * NN, 64, 0, stream>>>(x, A, ew1, eb1, hi, hj, d0);
  k_edge<<<B * 10, 256, 0, stream>>>(hi, hj, ew2, eb2, mask, Ah1, d1);
  k_gconv<32><<<B * 10, 256, 0, stream>>>(x,  A, Ah1, d0, d1, mask, gw0, gb0, h0);
  k_gconv<64><<<B * 10, 256, 0, stream>>>(h0, A, Ah1, d0, d1, mask, gw1, gb1, h1);
  k_gconv<64><<<B * 10, 256, 0, stream>>>(h1, A, Ah1, d0, d1, mask, gw2, gb2, h0);
  k_final<<<B, 64, 0, stream>>>(h0, fw, fb, out);
}